// Round 9
// baseline (180.482 us; speedup 1.0000x reference)
//
#include <hip/hip_runtime.h>
#include <stdint.h>

// RGCNConv: out = sum_r ((A * [edge==r]) @ x) @ W_r + bias
// N=4096, IN=OUT=256, R=8.
//   k_y    : yt2[(j*256+o)*8+r] = (x @ W_r)[j][o]  (bf16 granules, ws[0,16MB))
//   k_main : expanded GEMM out[i][o] += sum_j A[i][j]*yt2[j][o][e[i][j]]
//            256-thr blocks (4 waves, 2i x 2o, wave tile 64x64 m2n2),
//            4 blocks/CU (36KB LDS): independent barriers overlap the
//            per-block stalls that capped round 8 at 28% MfmaUtil.
//            3-deep stages, per-thread 6 DMAs/step, honest vmcnt(6).
//   epilogue: partials to ws + k_red (no atomics) if ws fits, else atomic.

#define NN 4096

typedef __attribute__((ext_vector_type(8)))  short s16x8;   // 8 bf16 MFMA frag
typedef __attribute__((ext_vector_type(16))) float f32x16;  // 32x32 C/D
typedef __attribute__((ext_vector_type(4)))  float fx4;
typedef __attribute__((ext_vector_type(4)))  int   ix4;
typedef __attribute__((ext_vector_type(4)))  unsigned int ux4;

union uq { ux4 u; s16x8 s; };

__device__ __forceinline__ unsigned short f2bf(float f) {
  union { float f; unsigned int u; } v; v.f = f;
  unsigned int r = v.u + 0x7fffu + ((v.u >> 16) & 1u);  // RNE
  return (unsigned short)(r >> 16);
}

__device__ __forceinline__ void gld16(const void* g, void* l) {
  __builtin_amdgcn_global_load_lds(
      (const __attribute__((address_space(1))) unsigned int*)(uintptr_t)g,
      (__attribute__((address_space(3))) unsigned int*)(uintptr_t)l, 16, 0, 0);
}
__device__ __forceinline__ void gld4(const void* g, void* l) {
  __builtin_amdgcn_global_load_lds(
      (const __attribute__((address_space(1))) unsigned int*)(uintptr_t)g,
      (__attribute__((address_space(3))) unsigned int*)(uintptr_t)l, 4, 0, 0);
}

// ---------------- init: out = bias (atomic fallback path only) -------------
__global__ void k_init(const float* __restrict__ bias, float* __restrict__ out) {
  int idx = blockIdx.x * 256 + threadIdx.x;
  out[idx] = bias[idx & 255];
}

// ---------------- yt2[(j*256+o)*8+r] = sum_k x[j][k] * W[r][k][o] ----------
__global__ __launch_bounds__(256, 2) void k_y(const float* __restrict__ x,
                                              const float* __restrict__ W,
                                              unsigned short* __restrict__ yt) {
  __shared__ unsigned short Wl[128 * 256];  // 64 KB
  const int t  = threadIdx.x;
  const int j0 = blockIdx.x * 128;
  const int o0 = blockIdx.y * 16;

  {
    const int r = t >> 5, kc = t & 31;
#pragma unroll
    for (int u = 0; u < 8; ++u) {
      const int k = kc * 8 + u;
      const fx4* wp = (const fx4*)(W + ((size_t)r * 256 + k) * 256 + o0);
      fx4 w[4] = { wp[0], wp[1], wp[2], wp[3] };
#pragma unroll
      for (int i = 0; i < 16; ++i) {
        const int row = i * 8 + r;               // n'
        const int gs  = (k >> 3) ^ (row & 7);    // swizzled 16B granule
        Wl[row * 256 + gs * 8 + (k & 7)] = f2bf(w[i >> 2][i & 3]);
      }
    }
  }
  __syncthreads();

  const int lane = t & 63, wid = t >> 6;
  const int l15 = lane & 15, lh = lane >> 4;
  const int npb = wid * 32;

  fx4 acc[8][2];
#pragma unroll
  for (int m = 0; m < 8; ++m)
#pragma unroll
    for (int n = 0; n < 2; ++n) acc[m][n] = 0.f;

  unsigned int qb[2];
#pragma unroll
  for (int n = 0; n < 2; ++n) {
    int row = npb + n * 16 + l15;
    qb[n] = (unsigned)(row * 512 + 16 * (lh ^ (row & 3))) ^ (64u * ((row >> 2) & 1));
  }
  const char* WlB = (const char*)Wl;
  const float* xb = x + (size_t)(j0 + l15) * 256 + lh * 8;

#pragma unroll
  for (int ks = 0; ks < 8; ++ks) {
    s16x8 a[8];
#pragma unroll
    for (int m = 0; m < 8; ++m) {
      const fx4* xp = (const fx4*)(xb + (size_t)m * 16 * 256 + ks * 32);
      fx4 x0 = xp[0], x1 = xp[1];
      s16x8 av;
#pragma unroll
      for (int i = 0; i < 4; ++i) av[i] = (short)f2bf(x0[i]);
#pragma unroll
      for (int i = 0; i < 4; ++i) av[4 + i] = (short)f2bf(x1[i]);
      a[m] = av;
    }
#pragma unroll
    for (int n = 0; n < 2; ++n) {
      s16x8 b = *(const s16x8*)(WlB + (qb[n] ^ (unsigned)(ks * 64)));
#pragma unroll
      for (int m = 0; m < 8; ++m)
        acc[m][n] = __builtin_amdgcn_mfma_f32_16x16x32_bf16(a[m], b, acc[m][n], 0, 0, 0);
    }
  }

#pragma unroll
  for (int m = 0; m < 8; ++m)
#pragma unroll
    for (int n = 0; n < 2; ++n)
#pragma unroll
      for (int q = 0; q < 4; ++q) {
        int jl = m * 16 + lh * 4 + q;
        int np = npb + n * 16 + l15;
        int o  = o0 + (np >> 3);
        yt[((size_t)(j0 + jl) * 256 + o) * 8 + (np & 7)] = f2bf(acc[m][n][q]);
      }
}

// ---------------- main expanded GEMM ----------------
// grid (32 itiles, 2 otiles, 16 ksplit) = 1024 blocks (4/CU). Block 128x128.
// 256 thr / 4 waves (2i x 2o), wave tile 64x64 = m2 x n2 32x32x16 reps.
// Step = 4 j (K_eff 32, 2 k-slices). j-local(ks,lh1) = ks*2 + lh1.
// Stage 12 KB: A [128 i][4 j]f32 @0, E @2K, B [4 plane][128 o]x16B @4K.
// 3 stages rotating. Per thread/step: 2 gld4(A) + 2 gld4(E) + 2 gld16(B).
// Top of iter: vmcnt(6) (stage s landed, s+1 in flight), s_barrier,
// issue stage s+2, readback (all ds_read_b128, conflict-free), build
// one-hot A frags in regs, setprio(1) MFMA x8 setprio(0).
__global__ __launch_bounds__(256, 4) void k_main(const float* __restrict__ A,
                                                 const int*   __restrict__ et,
                                                 const unsigned short* __restrict__ yt,
                                                 float* __restrict__ dst,
                                                 int usePart) {
  __shared__ ux4 smem[2304];  // 36864 B = 3 x 12 KB
  char* smc = (char*)smem;
  const int t = threadIdx.x, lane = t & 63, w = t >> 6;
  const int l31 = lane & 31, lh1 = lane >> 5;
  const int wm = w >> 1, wn = w & 1;
  const int i0 = blockIdx.x * 128;
  const int o0 = blockIdx.y * 128;
  const int kz = blockIdx.z;
  const int jb = kz * 256;

  // A/E DMA: round u (0..1): elem = u*256+t -> row=elem>>2, j=elem&3
  const float* srcA[2]; const int* srcE[2];
#pragma unroll
  for (int u = 0; u < 2; ++u) {
    int elem = u * 256 + t;
    size_t off = (size_t)(i0 + (elem >> 2)) * NN + jb + (elem & 3);
    srcA[u] = A + off; srcE[u] = et + off;
  }
  // B DMA: round u: plane = u*2 + (t>>7), o-local = t&127 (2KB coalesced runs)
  const ux4* ytg = (const ux4*)yt;
  const ux4* srcB[2];
#pragma unroll
  for (int u = 0; u < 2; ++u)
    srcB[u] = ytg + ((size_t)jb + u * 2 + (t >> 7)) * 256 + o0 + (t & 127);

#define ISSUE(sq, pbase) do {                                              \
    _Pragma("unroll")                                                      \
    for (int u = 0; u < 2; ++u)                                            \
      gld4(srcA[u] + (size_t)(sq) * 4, smc + (pbase) + u * 1024 + w * 256);\
    _Pragma("unroll")                                                      \
    for (int u = 0; u < 2; ++u)                                            \
      gld4(srcE[u] + (size_t)(sq) * 4,                                     \
           smc + (pbase) + 2048 + u * 1024 + w * 256);                     \
    _Pragma("unroll")                                                      \
    for (int u = 0; u < 2; ++u)                                            \
      gld16(srcB[u] + (size_t)(sq) * 1024,                                 \
            smc + (pbase) + 4096 + u * 4096 + w * 1024);                   \
  } while (0)

  // readback offsets (all b128, lanes contiguous -> conflict-free)
  unsigned rA[2], rB[2][2];
#pragma unroll
  for (int m = 0; m < 2; ++m)
    rA[m] = (unsigned)((wm * 64 + m * 32 + l31) * 16);
#pragma unroll
  for (int ks = 0; ks < 2; ++ks)
#pragma unroll
    for (int n = 0; n < 2; ++n)
      rB[ks][n] = (unsigned)(4096 + ((ks * 2 + lh1) * 128 + wn * 64 + n * 32 + l31) * 16);

  f32x16 acc[2][2];
#pragma unroll
  for (int m = 0; m < 2; ++m)
#pragma unroll
    for (int n = 0; n < 2; ++n) acc[m][n] = 0.f;

  // prologue: 2 stages in flight
  ISSUE(0, 0);
  ISSUE(1, 12288);

  int pb0 = 0, pb1 = 12288, pb2 = 24576;
  for (int s = 0; s < 64; ++s) {
    asm volatile("s_waitcnt vmcnt(6)" ::: "memory");  // stage s landed
    __builtin_amdgcn_s_barrier();                     // all waves' stage s visible
    {
      const int sq = (s + 2 < 64) ? s + 2 : 63;       // tail dup-issue: benign
      ISSUE(sq, pb2);
    }
    // readback A/E (4 b128) and build frags per ks on the fly
    fx4 av[2]; ix4 ev[2];
#pragma unroll
    for (int m = 0; m < 2; ++m) {
      av[m] = *(const fx4*)(smc + pb0 + rA[m]);
      ev[m] = *(const ix4*)(smc + pb0 + 2048 + rA[m]);
    }
    __builtin_amdgcn_s_setprio(1);
#pragma unroll
    for (int ks = 0; ks < 2; ++ks) {
      uq a[2], b[2];
#pragma unroll
      for (int m = 0; m < 2; ++m) {
        float avv = lh1 ? av[m][ks * 2 + 1] : av[m][ks * 2];
        int   evv = lh1 ? ev[m][ks * 2 + 1] : ev[m][ks * 2];
        unsigned long long sh = ((unsigned long long)f2bf(avv)) << ((evv & 3) * 16);
        unsigned lo = (unsigned)sh, hi = (unsigned)(sh >> 32);
        bool c = evv < 4;
        ux4 q; q.x = c ? lo : 0u; q.y = c ? hi : 0u; q.z = c ? 0u : lo; q.w = c ? 0u : hi;
        a[m].u = q;
      }
#pragma unroll
      for (int n = 0; n < 2; ++n)
        b[n].u = *(const ux4*)(smc + pb0 + rB[ks][n]);
#pragma unroll
      for (int m = 0; m < 2; ++m)
#pragma unroll
        for (int n = 0; n < 2; ++n)
          acc[m][n] = __builtin_amdgcn_mfma_f32_32x32x16_bf16(a[m].s, b[n].s, acc[m][n], 0, 0, 0);
    }
    __builtin_amdgcn_s_setprio(0);
    int tmp = pb0; pb0 = pb1; pb1 = pb2; pb2 = tmp;
  }
  asm volatile("s_waitcnt vmcnt(0)" ::: "memory");  // drain DMA before exit

  // epilogue. 32x32 C layout: col = l31, row = (q&3) + 8*(q>>2) + 4*lh1
  if (usePart) {
    float* pp = dst + ((size_t)kz << 20);
#pragma unroll
    for (int m = 0; m < 2; ++m)
#pragma unroll
      for (int n = 0; n < 2; ++n)
#pragma unroll
        for (int q = 0; q < 16; ++q) {
          int gi = i0 + wm * 64 + m * 32 + (q & 3) + 8 * (q >> 2) + 4 * lh1;
          int go = o0 + wn * 64 + n * 32 + l31;
          pp[(size_t)gi * 256 + go] = acc[m][n][q];
        }
  } else {
#pragma unroll
    for (int m = 0; m < 2; ++m)
#pragma unroll
      for (int n = 0; n < 2; ++n)
#pragma unroll
        for (int q = 0; q < 16; ++q) {
          int gi = i0 + wm * 64 + m * 32 + (q & 3) + 8 * (q >> 2) + 4 * lh1;
          int go = o0 + wn * 64 + n * 32 + l31;
          atomicAdd(dst + (size_t)gi * 256 + go, acc[m][n][q]);
        }
  }
#undef ISSUE
}

// ---------------- reduce 16 partials + bias -> out ----------------
__global__ __launch_bounds__(256) void k_red(const float* __restrict__ part,
                                             const float* __restrict__ bias,
                                             float* __restrict__ out) {
  int idx = blockIdx.x * 256 + threadIdx.x;           // fx4 index, 262144 total
  fx4 s = *(const fx4*)(bias + ((idx << 2) & 255));
  const fx4* p4 = (const fx4*)part;
#pragma unroll
  for (int k = 0; k < 16; ++k) s += p4[((size_t)k << 18) + idx];
  ((fx4*)out)[idx] = s;
}

extern "C" void kernel_launch(void* const* d_in, const int* in_sizes, int n_in,
                              void* d_out, int out_size, void* d_ws, size_t ws_size,
                              hipStream_t stream) {
  const float* x    = (const float*)d_in[0];
  const float* A    = (const float*)d_in[1];
  const int*   et   = (const int*)d_in[2];
  const float* W    = (const float*)d_in[3];
  const float* bias = (const float*)d_in[4];
  float* out = (float*)d_out;
  unsigned short* yt = (unsigned short*)d_ws;  // 16 MB granule-major yt2

  const size_t YT = (size_t)16 << 20;
  const bool usePart = ws_size >= YT + ((size_t)64 << 20);

  k_y<<<dim3(32, 16), dim3(256), 0, stream>>>(x, W, yt);
  if (usePart) {
    float* pbuf = (float*)((char*)d_ws + YT);  // 16 x 4MB f32 partials
    k_main<<<dim3(32, 2, 16), dim3(256), 0, stream>>>(A, et, yt, pbuf, 1);
    k_red<<<dim3(1024), dim3(256), 0, stream>>>(pbuf, bias, out);
  } else {
    k_init<<<dim3(4096), dim3(256), 0, stream>>>(bias, out);
    k_main<<<dim3(32, 2, 16), dim3(256), 0, stream>>>(A, et, yt, out, 0);
  }
}

// Round 10
// 148.972 us; speedup vs baseline: 1.2115x; 1.2115x over previous
//
#include <hip/hip_runtime.h>
#include <stdint.h>

// RGCNConv: out = sum_r ((A * [edge==r]) @ x) @ W_r + bias
// N=4096, IN=OUT=256, R=8.
//   k_t    : transpose-pack A+et -> Apk[(jg*4096+i)] granule of 8 u16
//            (u16 = [e:3][exp4:4][mant9], sign-free since A in [0,1)).
//            Kills the per-lane scatter every prior round paid in k_main.
//   k_y    : yt[(j*256+o)*8+r] = (x @ W_r)[j][o]  bf16 granules.
//   k_main : expanded GEMM, step = 1 jg (8 j = K_eff 64). A direct
//            global->reg (coalesced b128); B via global_load_lds 3-deep;
//            uniform 6 VMEM/thread/step, honest vmcnt(6), 1 barrier/step.
//   k_red  : sum 16 f16 partials + bias.
// ws: yt 16MB @0, Apk 32MB @16MB, partials f16 32MB @48MB (=80MB).

#define NN 4096

typedef __attribute__((ext_vector_type(8)))  short s16x8;   // 8 bf16 MFMA frag
typedef __attribute__((ext_vector_type(16))) float f32x16;  // 32x32 C/D
typedef __attribute__((ext_vector_type(4)))  float fx4;
typedef __attribute__((ext_vector_type(4)))  int   ix4;
typedef __attribute__((ext_vector_type(4)))  unsigned int ux4;
typedef __attribute__((ext_vector_type(4)))  _Float16 h4;

union uq { ux4 u; s16x8 s; };

__device__ __forceinline__ unsigned short f2bf(float f) {
  union { float f; unsigned int u; } v; v.f = f;
  unsigned int r = v.u + 0x7fffu + ((v.u >> 16) & 1u);  // RNE
  return (unsigned short)(r >> 16);
}

__device__ __forceinline__ void gld16(const void* g, void* l) {
  __builtin_amdgcn_global_load_lds(
      (const __attribute__((address_space(1))) unsigned int*)(uintptr_t)g,
      (__attribute__((address_space(3))) unsigned int*)(uintptr_t)l, 16, 0, 0);
}

// pack (a in [0,1), e in 0..7) -> u16 [e:3][exp4:4][mant9]
__device__ __forceinline__ unsigned packAE(float a, int e) {
  unsigned ab = __float_as_uint(a) + 0x2000u;   // round mant9 (carry-safe)
  unsigned ex = ab >> 23;                       // sign=0 always
  int el = (int)ex - 112;                       // 1..15 valid
  unsigned m9 = (ab >> 14) & 0x1FFu;
  unsigned v = ((unsigned)el << 9) | m9;
  if (el <= 0) v = 0;                           // tiny -> 0 (neg err ~6e-5)
  return (unsigned short)(((unsigned)e << 13) | (v & 0x1FFFu));
}

// ---------------- init (atomic fallback path only) ----------------
__global__ void k_init(const float* __restrict__ bias, float* __restrict__ out) {
  int idx = blockIdx.x * 256 + threadIdx.x;
  out[idx] = bias[idx & 255];
}

// ---------------- k_t: A,et -> Apk granules ----------------
// grid (128 itiles, 8 jtiles), 256 thr. Tile 32 i x 512 j.
// LDS [64 jg][129 dwords] (pad 1 dword/row -> writes ~2-way, reads ~4-way).
__global__ __launch_bounds__(256, 2) void k_t(const float* __restrict__ A,
                                              const int*   __restrict__ et,
                                              unsigned short* __restrict__ Apk) {
  __shared__ unsigned int lds[64 * 129];  // 33 KB
  const int t = threadIdx.x;
  const int ib = blockIdx.x * 32;
  const int jb = blockIdx.y * 512;
  const int jgb = blockIdx.y * 64;

#pragma unroll
  for (int u = 0; u < 16; ++u) {
    const int row = u * 2 + (t >> 7);
    const int jl  = (t & 127) * 4;
    const size_t off = (size_t)(ib + row) * NN + jb + jl;
    fx4 a = *(const fx4*)(A + off);
    ix4 e = *(const ix4*)(et + off);
    unsigned d0 = (unsigned)packAE(a.x, e.x) | ((unsigned)packAE(a.y, e.y) << 16);
    unsigned d1 = (unsigned)packAE(a.z, e.z) | ((unsigned)packAE(a.w, e.w) << 16);
    const int jg = jl >> 3;
    const int dd = ((jl & 7) >> 1);           // 0 or 2
    lds[jg * 129 + row * 4 + dd]     = d0;
    lds[jg * 129 + row * 4 + dd + 1] = d1;
  }
  __syncthreads();

  const int lane = t & 63, lh1 = (t >> 5) & 1, l31 = t & 31;
  const int wv = t >> 6;
#pragma unroll
  for (int v = 0; v < 8; ++v) {
    const int jg = (wv * 8 + v) * 2 + lh1;    // 0..63
    const int base = jg * 129 + l31 * 4;
    ux4 q;
    q.x = lds[base]; q.y = lds[base + 1]; q.z = lds[base + 2]; q.w = lds[base + 3];
    ((ux4*)Apk)[(size_t)(jgb + jg) * NN + ib + l31] = q;
  }
  (void)lane;
}

// ---------------- k_y: yt[(j*256+o)*8+r] = sum_k x[j][k]*W[r][k][o] ----------
__global__ __launch_bounds__(256, 2) void k_y(const float* __restrict__ x,
                                              const float* __restrict__ W,
                                              unsigned short* __restrict__ yt) {
  __shared__ unsigned short Wl[128 * 256];  // 64 KB
  const int t  = threadIdx.x;
  const int j0 = blockIdx.x * 128;
  const int o0 = blockIdx.y * 16;

  {
    const int r = t >> 5, kc = t & 31;
#pragma unroll
    for (int u = 0; u < 8; ++u) {
      const int k = kc * 8 + u;
      const fx4* wp = (const fx4*)(W + ((size_t)r * 256 + k) * 256 + o0);
      fx4 w[4] = { wp[0], wp[1], wp[2], wp[3] };
#pragma unroll
      for (int i = 0; i < 16; ++i) {
        const int row = i * 8 + r;
        const int gs  = (k >> 3) ^ (row & 7);
        Wl[row * 256 + gs * 8 + (k & 7)] = f2bf(w[i >> 2][i & 3]);
      }
    }
  }
  __syncthreads();

  const int lane = t & 63, wid = t >> 6;
  const int l15 = lane & 15, lh = lane >> 4;
  const int npb = wid * 32;

  fx4 acc[8][2];
#pragma unroll
  for (int m = 0; m < 8; ++m)
#pragma unroll
    for (int n = 0; n < 2; ++n) acc[m][n] = 0.f;

  unsigned int qb[2];
#pragma unroll
  for (int n = 0; n < 2; ++n) {
    int row = npb + n * 16 + l15;
    qb[n] = (unsigned)(row * 512 + 16 * (lh ^ (row & 3))) ^ (64u * ((row >> 2) & 1));
  }
  const char* WlB = (const char*)Wl;
  const float* xb = x + (size_t)(j0 + l15) * 256 + lh * 8;

#pragma unroll
  for (int ks = 0; ks < 8; ++ks) {
    s16x8 a[8];
#pragma unroll
    for (int m = 0; m < 8; ++m) {
      const fx4* xp = (const fx4*)(xb + (size_t)m * 16 * 256 + ks * 32);
      fx4 x0 = xp[0], x1 = xp[1];
      s16x8 av;
#pragma unroll
      for (int i = 0; i < 4; ++i) av[i] = (short)f2bf(x0[i]);
#pragma unroll
      for (int i = 0; i < 4; ++i) av[4 + i] = (short)f2bf(x1[i]);
      a[m] = av;
    }
#pragma unroll
    for (int n = 0; n < 2; ++n) {
      s16x8 b = *(const s16x8*)(WlB + (qb[n] ^ (unsigned)(ks * 64)));
#pragma unroll
      for (int m = 0; m < 8; ++m)
        acc[m][n] = __builtin_amdgcn_mfma_f32_16x16x32_bf16(a[m], b, acc[m][n], 0, 0, 0);
    }
  }

#pragma unroll
  for (int m = 0; m < 8; ++m)
#pragma unroll
    for (int n = 0; n < 2; ++n)
#pragma unroll
      for (int q = 0; q < 4; ++q) {
        int jl = m * 16 + lh * 4 + q;
        int np = npb + n * 16 + l15;
        int o  = o0 + (np >> 3);
        yt[((size_t)(j0 + jl) * 256 + o) * 8 + (np & 7)] = f2bf(acc[m][n][q]);
      }
}

// ---------------- k_main ----------------
// grid (32 i, 2 o, 16 kz) = 1024 blocks (3/CU by LDS). Block 128x128,
// 256 thr / 4 waves (2i x 2o), wave tile 64x64 = m2 x n2 32x32x16.
// Step = 1 jg (8 j, K_eff 64, ks 0..3; lane lh1 -> j = 2ks+lh1).
// A: direct coalesced b128/lane from Apk (granule = 8 u16, e folded).
// B: LDS 3 x 16KB (8 planes x 128 o x 16B) via gld16, linear.
// Per thread/step: 4 B-DMA + 2 A-loads = 6 VMEM. Top: vmcnt(6), barrier.
__global__ __launch_bounds__(256, 3) void k_main(const unsigned short* __restrict__ Apk,
                                                 const unsigned short* __restrict__ yt,
                                                 float* __restrict__ dstF,
                                                 _Float16* __restrict__ dstH,
                                                 int usePart) {
  __shared__ ux4 Bl[3 * 1024];  // 48 KB
  char* Bc = (char*)Bl;
  const int t = threadIdx.x, lane = t & 63, w = t >> 6;
  const int l31 = lane & 31, lh1 = lane >> 5;
  const int wm = w >> 1, wn = w & 1;
  const int i0 = blockIdx.x * 128;
  const int o0 = blockIdx.y * 128;
  const int kz = blockIdx.z;
  const int jb = kz * 256;          // j-window 256 = 32 jg-steps
  const int jg0 = kz * 32;

  // A sources: per m one granule ptr (ux4), step stride 4096 granules
  const ux4* pA[2];
#pragma unroll
  for (int m = 0; m < 2; ++m)
    pA[m] = (const ux4*)Apk + (size_t)jg0 * NN + i0 + wm * 64 + m * 32 + l31;

  // B DMA sources + LDS dests (linear, wave-uniform-base + lane*16)
  const ux4* ytg = (const ux4*)yt;
  const ux4* pB[4];
  unsigned dOff[4];
#pragma unroll
  for (int u = 0; u < 4; ++u) {
    int slot = u * 256 + t;
    pB[u] = ytg + (size_t)(jb + (slot >> 7)) * 256 + o0 + (slot & 127);
    dOff[u] = (unsigned)(slot * 16);
  }

#define ISSUE(sq, bb, ASET) do {                                          \
    _Pragma("unroll")                                                     \
    for (int u = 0; u < 4; ++u)                                           \
      gld16(pB[u] + (size_t)(sq) * 2048, Bc + (bb) * 16384 + dOff[u]);    \
    ASET[0] = pA[0][(size_t)(sq) * NN];                                   \
    ASET[1] = pA[1][(size_t)(sq) * NN];                                   \
  } while (0)

  // build all 8 one-hot frags from an A-set (pure VALU)
  const unsigned shA = (unsigned)(lh1 * 16);
#define BUILD(ASET, FR) do {                                              \
    _Pragma("unroll")                                                     \
    for (int m = 0; m < 2; ++m)                                           \
      _Pragma("unroll")                                                   \
      for (int ks = 0; ks < 4; ++ks) {                                    \
        unsigned u16 = (ASET[m][ks] >> shA) & 0xFFFFu;                    \
        unsigned a16 = 0x3800u | ((u16 >> 2) & 0x7FFu);                   \
        unsigned e   = u16 >> 13;                                         \
        unsigned long long sh = (unsigned long long)a16 << ((e & 3u) << 4); \
        unsigned lo = (unsigned)sh, hi = (unsigned)(sh >> 32);            \
        bool c = e < 4;                                                   \
        ux4 q; q.x = c ? lo : 0u; q.y = c ? hi : 0u;                      \
        q.z = c ? 0u : lo; q.w = c ? 0u : hi;                             \
        FR[m][ks].u = q;                                                  \
      }                                                                   \
  } while (0)

  unsigned rB[2];
#pragma unroll
  for (int n = 0; n < 2; ++n)
    rB[n] = (unsigned)((wn * 64 + n * 32 + l31) * 16);

#define COMPUTE(bb, FR) do {                                              \
    const unsigned base = (unsigned)((bb) * 16384) + (unsigned)(lh1 * 2048); \
    _Pragma("unroll")                                                     \
    for (int ks = 0; ks < 4; ++ks) {                                      \
      uq b0, b1;                                                          \
      b0.u = *(const ux4*)(Bc + base + (unsigned)(ks * 4096) + rB[0]);    \
      b1.u = *(const ux4*)(Bc + base + (unsigned)(ks * 4096) + rB[1]);    \
      _Pragma("unroll")                                                   \
      for (int m = 0; m < 2; ++m) {                                       \
        acc[m][0] = __builtin_amdgcn_mfma_f32_32x32x16_bf16(FR[m][ks].s, b0.s, acc[m][0], 0, 0, 0); \
        acc[m][1] = __builtin_amdgcn_mfma_f32_32x32x16_bf16(FR[m][ks].s, b1.s, acc[m][1], 0, 0, 0); \
      }                                                                   \
    }                                                                     \
  } while (0)

  f32x16 acc[2][2];
#pragma unroll
  for (int m = 0; m < 2; ++m)
#pragma unroll
    for (int n = 0; n < 2; ++n) acc[m][n] = 0.f;

  ux4 aE[2], aO[2];
  uq frE[2][4], frO[2][4];

  ISSUE(0, 0, aE);
  ISSUE(1, 1, aO);

  for (int s = 0; s < 32; s += 2) {
    const int sq2 = (s + 2 < 32) ? s + 2 : 31;
    const int sq3 = (s + 3 < 32) ? s + 3 : 31;
    const int b0 = s % 3, b1 = (s + 1) % 3, b2 = (s + 2) % 3;
    // even step s
    asm volatile("s_waitcnt vmcnt(6)" ::: "memory");
    __builtin_amdgcn_s_barrier();
    BUILD(aE, frE);                 // consume aE fully...
    ISSUE(sq2, b2, aE);             // ...then re-issue into it
    __builtin_amdgcn_s_setprio(1);
    COMPUTE(b0, frE);
    __builtin_amdgcn_s_setprio(0);
    // odd step s+1
    asm volatile("s_waitcnt vmcnt(6)" ::: "memory");
    __builtin_amdgcn_s_barrier();
    BUILD(aO, frO);
    ISSUE(sq3, b0, aO);
    __builtin_amdgcn_s_setprio(1);
    COMPUTE(b1, frO);
    __builtin_amdgcn_s_setprio(0);
  }
  asm volatile("s_waitcnt vmcnt(0)" ::: "memory");  // drain before exit

  // epilogue. 32x32 C layout: col = l31, row = (q&3) + 8*(q>>2) + 4*lh1
  if (usePart) {
    _Float16* pp = dstH + ((size_t)kz << 20);
#pragma unroll
    for (int m = 0; m < 2; ++m)
#pragma unroll
      for (int n = 0; n < 2; ++n)
#pragma unroll
        for (int q = 0; q < 16; ++q) {
          int gi = i0 + wm * 64 + m * 32 + (q & 3) + 8 * (q >> 2) + 4 * lh1;
          int go = o0 + wn * 64 + n * 32 + l31;
          pp[(size_t)gi * 256 + go] = (_Float16)acc[m][n][q];
        }
  } else {
#pragma unroll
    for (int m = 0; m < 2; ++m)
#pragma unroll
      for (int n = 0; n < 2; ++n)
#pragma unroll
        for (int q = 0; q < 16; ++q) {
          int gi = i0 + wm * 64 + m * 32 + (q & 3) + 8 * (q >> 2) + 4 * lh1;
          int go = o0 + wn * 64 + n * 32 + l31;
          atomicAdd(dstF + (size_t)gi * 256 + go, acc[m][n][q]);
        }
  }
#undef ISSUE
#undef BUILD
#undef COMPUTE
}

// ---------------- k_red: sum 16 f16 partials + bias -> out ----------------
__global__ __launch_bounds__(256) void k_red(const _Float16* __restrict__ part,
                                             const float* __restrict__ bias,
                                             float* __restrict__ out) {
  int idx = blockIdx.x * 256 + threadIdx.x;     // 262144 fx4-groups
  fx4 s = *(const fx4*)(bias + ((idx << 2) & 255));
#pragma unroll
  for (int k = 0; k < 16; ++k) {
    h4 h = *(const h4*)(part + ((size_t)k << 20) + (size_t)idx * 4);
    s.x += (float)h.x; s.y += (float)h.y; s.z += (float)h.z; s.w += (float)h.w;
  }
  ((fx4*)out)[idx] = s;
}

extern "C" void kernel_launch(void* const* d_in, const int* in_sizes, int n_in,
                              void* d_out, int out_size, void* d_ws, size_t ws_size,
                              hipStream_t stream) {
  const float* x    = (const float*)d_in[0];
  const float* A    = (const float*)d_in[1];
  const int*   et   = (const int*)d_in[2];
  const float* W    = (const float*)d_in[3];
  const float* bias = (const float*)d_in[4];
  float* out = (float*)d_out;

  unsigned short* yt  = (unsigned short*)d_ws;                         // 16 MB
  unsigned short* Apk = (unsigned short*)((char*)d_ws + ((size_t)16 << 20)); // 32 MB
  _Float16*       pp  = (_Float16*)((char*)d_ws + ((size_t)48 << 20)); // 32 MB

  const bool usePart = ws_size >= ((size_t)80 << 20);

  k_t<<<dim3(128, 8), dim3(256), 0, stream>>>(A, et, Apk);
  k_y<<<dim3(32, 16), dim3(256), 0, stream>>>(x, W, yt);
  if (usePart) {
    k_main<<<dim3(32, 2, 16), dim3(256), 0, stream>>>(Apk, yt, out, pp, 1);
    k_red<<<dim3(1024), dim3(256), 0, stream>>>(pp, bias, out);
  } else {
    k_init<<<dim3(4096), dim3(256), 0, stream>>>(bias, out);
    k_main<<<dim3(32, 2, 16), dim3(256), 0, stream>>>(Apk, yt, out, pp, 0);
  }
}

// Round 11
// 143.866 us; speedup vs baseline: 1.2545x; 1.0355x over previous
//
#include <hip/hip_runtime.h>
#include <stdint.h>

// RGCNConv: out = sum_r ((A * [edge==r]) @ x) @ W_r + bias
// N=4096, IN=OUT=256, R=8.
//   k_prep : FUSED {k_t: transpose-pack A+et -> Apk[(jg*4096+i)] granules of
//            8 u16 ([e:3][exp4:4][mant9])} and {k_y: yt[(j*256+o)*8+r] =
//            (x@W_r)[j][o] bf16 granules} — role split on blockIdx so the
//            VALU-heavy pack overlaps the MFMA-heavy GEMM.
//   k_main : expanded GEMM, step = 1 jg (8 j = K_eff 64). A direct
//            global->reg (coalesced b128 of packed granules); B via
//            global_load_lds 3-deep; 6 VMEM/thread/step, honest vmcnt(6),
//            1 barrier/step. 1-D grid with kz->XCD swizzle (b%8 == kz%8)
//            so each kz's yt window (512KB) + Apk slice stay in one L2.
//   k_red  : sum 16 f16 partials + bias.
// ws: yt 16MB @0, Apk 32MB @16MB, partials f16 32MB @48MB (=80MB).

#define NN 4096

typedef __attribute__((ext_vector_type(8)))  short s16x8;   // 8 bf16 MFMA frag
typedef __attribute__((ext_vector_type(16))) float f32x16;  // 32x32 C/D
typedef __attribute__((ext_vector_type(4)))  float fx4;
typedef __attribute__((ext_vector_type(4)))  int   ix4;
typedef __attribute__((ext_vector_type(4)))  unsigned int ux4;
typedef __attribute__((ext_vector_type(4)))  _Float16 h4;

union uq { ux4 u; s16x8 s; };

__device__ __forceinline__ unsigned short f2bf(float f) {
  union { float f; unsigned int u; } v; v.f = f;
  unsigned int r = v.u + 0x7fffu + ((v.u >> 16) & 1u);  // RNE
  return (unsigned short)(r >> 16);
}

__device__ __forceinline__ void gld16(const void* g, void* l) {
  __builtin_amdgcn_global_load_lds(
      (const __attribute__((address_space(1))) unsigned int*)(uintptr_t)g,
      (__attribute__((address_space(3))) unsigned int*)(uintptr_t)l, 16, 0, 0);
}

// pack (a in [0,1), e in 0..7) -> u16 [e:3][exp4:4][mant9]
__device__ __forceinline__ unsigned packAE(float a, int e) {
  unsigned ab = __float_as_uint(a) + 0x2000u;   // round mant9 (carry-safe)
  unsigned ex = ab >> 23;
  int el = (int)ex - 112;                       // 1..15 valid
  unsigned m9 = (ab >> 14) & 0x1FFu;
  unsigned v = ((unsigned)el << 9) | m9;
  if (el <= 0) v = 0;                           // tiny -> 0 (neg err ~6e-5)
  return (unsigned short)(((unsigned)e << 13) | (v & 0x1FFFu));
}

// ---------------- init (atomic fallback path only) ----------------
__global__ void k_init(const float* __restrict__ bias, float* __restrict__ out) {
  int idx = blockIdx.x * 256 + threadIdx.x;
  out[idx] = bias[idx & 255];
}

// ---------------- k_prep: fused transpose-pack (blocks 0..1023) ----------------
//                  and y-GEMM (blocks 1024..1535)
__global__ __launch_bounds__(256, 2) void k_prep(const float* __restrict__ A,
                                                 const int*   __restrict__ et,
                                                 unsigned short* __restrict__ Apk,
                                                 const float* __restrict__ x,
                                                 const float* __restrict__ W,
                                                 unsigned short* __restrict__ yt) {
  __shared__ char smraw[65536];  // k_t uses 33KB as u32[64*129]; k_y 64KB u16
  const int t = threadIdx.x;

  if (blockIdx.x < 1024) {
    // ---- k_t role: tile 32 i x 512 j ----
    unsigned int* lds = (unsigned int*)smraw;   // [64 jg][129 dwords] (pad)
    const int b  = blockIdx.x;
    const int ib = (b & 127) * 32;
    const int byy = b >> 7;
    const int jb = byy * 512;
    const int jgb = byy * 64;

#pragma unroll
    for (int u = 0; u < 16; ++u) {
      const int row = u * 2 + (t >> 7);
      const int jl  = (t & 127) * 4;
      const size_t off = (size_t)(ib + row) * NN + jb + jl;
      fx4 a = *(const fx4*)(A + off);
      ix4 e = *(const ix4*)(et + off);
      unsigned d0 = (unsigned)packAE(a.x, e.x) | ((unsigned)packAE(a.y, e.y) << 16);
      unsigned d1 = (unsigned)packAE(a.z, e.z) | ((unsigned)packAE(a.w, e.w) << 16);
      const int jg = jl >> 3;
      const int dd = ((jl & 7) >> 1);           // 0 or 2
      lds[jg * 129 + row * 4 + dd]     = d0;
      lds[jg * 129 + row * 4 + dd + 1] = d1;
    }
    __syncthreads();

    const int lh1 = (t >> 5) & 1, l31 = t & 31;
    const int wv = t >> 6;
#pragma unroll
    for (int v = 0; v < 8; ++v) {
      const int jg = (wv * 8 + v) * 2 + lh1;    // 0..63
      const int base = jg * 129 + l31 * 4;
      ux4 q;
      q.x = lds[base]; q.y = lds[base + 1]; q.z = lds[base + 2]; q.w = lds[base + 3];
      ((ux4*)Apk)[(size_t)(jgb + jg) * NN + ib + l31] = q;
    }
    return;
  }

  // ---- k_y role ----
  unsigned short* Wl = (unsigned short*)smraw;  // [128 n'][256 k]
  const int b2 = blockIdx.x - 1024;             // 0..511
  const int j0 = (b2 & 31) * 128;
  const int o0 = (b2 >> 5) * 16;

  {
    const int r = t >> 5, kc = t & 31;
#pragma unroll
    for (int u = 0; u < 8; ++u) {
      const int k = kc * 8 + u;
      const fx4* wp = (const fx4*)(W + ((size_t)r * 256 + k) * 256 + o0);
      fx4 w[4] = { wp[0], wp[1], wp[2], wp[3] };
#pragma unroll
      for (int i = 0; i < 16; ++i) {
        const int row = i * 8 + r;
        const int gs  = (k >> 3) ^ (row & 7);
        Wl[row * 256 + gs * 8 + (k & 7)] = f2bf(w[i >> 2][i & 3]);
      }
    }
  }
  __syncthreads();

  const int lane = t & 63, wid = t >> 6;
  const int l15 = lane & 15, lh = lane >> 4;
  const int npb = wid * 32;

  fx4 acc[8][2];
#pragma unroll
  for (int m = 0; m < 8; ++m)
#pragma unroll
    for (int n = 0; n < 2; ++n) acc[m][n] = 0.f;

  unsigned int qb[2];
#pragma unroll
  for (int n = 0; n < 2; ++n) {
    int row = npb + n * 16 + l15;
    qb[n] = (unsigned)(row * 512 + 16 * (lh ^ (row & 3))) ^ (64u * ((row >> 2) & 1));
  }
  const char* WlB = (const char*)Wl;
  const float* xb = x + (size_t)(j0 + l15) * 256 + lh * 8;

#pragma unroll
  for (int ks = 0; ks < 8; ++ks) {
    s16x8 a[8];
#pragma unroll
    for (int m = 0; m < 8; ++m) {
      const fx4* xp = (const fx4*)(xb + (size_t)m * 16 * 256 + ks * 32);
      fx4 x0 = xp[0], x1 = xp[1];
      s16x8 av;
#pragma unroll
      for (int i = 0; i < 4; ++i) av[i] = (short)f2bf(x0[i]);
#pragma unroll
      for (int i = 0; i < 4; ++i) av[4 + i] = (short)f2bf(x1[i]);
      a[m] = av;
    }
#pragma unroll
    for (int n = 0; n < 2; ++n) {
      s16x8 bb = *(const s16x8*)(WlB + (qb[n] ^ (unsigned)(ks * 64)));
#pragma unroll
      for (int m = 0; m < 8; ++m)
        acc[m][n] = __builtin_amdgcn_mfma_f32_16x16x32_bf16(a[m], bb, acc[m][n], 0, 0, 0);
    }
  }

#pragma unroll
  for (int m = 0; m < 8; ++m)
#pragma unroll
    for (int n = 0; n < 2; ++n)
#pragma unroll
      for (int q = 0; q < 4; ++q) {
        int jl = m * 16 + lh * 4 + q;
        int np = npb + n * 16 + l15;
        int o  = o0 + (np >> 3);
        yt[((size_t)(j0 + jl) * 256 + o) * 8 + (np & 7)] = f2bf(acc[m][n][q]);
      }
}

// ---------------- k_main ----------------
// 1-D grid 1024: b = io*16 + kz  (kz = b&15 -> XCD b%8 = kz%8: one kz's yt
// window + Apk slice pinned to one XCD L2). io: i0 = (io>>1)*128,
// o0 = (io&1)*128. Block 128x128, 4 waves (2i x 2o), wave tile 64x64
// (m2 x n2 32x32x16). Step = 1 jg (8 j, K_eff 64).
// A: coalesced b128/lane from Apk. B: LDS 3 x 16KB via gld16, linear.
// Per thread/step: 4 B-DMA + 2 A = 6 VMEM. Top: vmcnt(6), s_barrier.
__global__ __launch_bounds__(256, 3) void k_main(const unsigned short* __restrict__ Apk,
                                                 const unsigned short* __restrict__ yt,
                                                 float* __restrict__ dstF,
                                                 _Float16* __restrict__ dstH,
                                                 int usePart) {
  __shared__ ux4 Bl[3 * 1024];  // 48 KB
  char* Bc = (char*)Bl;
  const int t = threadIdx.x, lane = t & 63, w = t >> 6;
  const int l31 = lane & 31, lh1 = lane >> 5;
  const int wm = w >> 1, wn = w & 1;
  const int b = blockIdx.x;
  const int kz = b & 15;
  const int io = b >> 4;
  const int i0 = (io >> 1) * 128;
  const int o0 = (io & 1) * 128;
  const int jb = kz * 256;          // j-window 256 = 32 jg-steps
  const int jg0 = kz * 32;

  // A sources: per m one granule ptr (ux4), step stride 4096 granules
  const ux4* pA[2];
#pragma unroll
  for (int m = 0; m < 2; ++m)
    pA[m] = (const ux4*)Apk + (size_t)jg0 * NN + i0 + wm * 64 + m * 32 + l31;

  // B DMA sources + LDS dests (linear, wave-uniform base + lane*16)
  const ux4* ytg = (const ux4*)yt;
  const ux4* pB[4];
  unsigned dOff[4];
#pragma unroll
  for (int u = 0; u < 4; ++u) {
    int slot = u * 256 + t;
    pB[u] = ytg + (size_t)(jb + (slot >> 7)) * 256 + o0 + (slot & 127);
    dOff[u] = (unsigned)(slot * 16);
  }

#define ISSUE(sq, bb, ASET) do {                                          \
    _Pragma("unroll")                                                     \
    for (int u = 0; u < 4; ++u)                                           \
      gld16(pB[u] + (size_t)(sq) * 2048, Bc + (bb) * 16384 + dOff[u]);    \
    ASET[0] = pA[0][(size_t)(sq) * NN];                                   \
    ASET[1] = pA[1][(size_t)(sq) * NN];                                   \
  } while (0)

  const unsigned shA = (unsigned)(lh1 * 16);
#define BUILD(ASET, FR) do {                                              \
    _Pragma("unroll")                                                     \
    for (int m = 0; m < 2; ++m)                                           \
      _Pragma("unroll")                                                   \
      for (int ks = 0; ks < 4; ++ks) {                                    \
        unsigned u16 = (ASET[m][ks] >> shA) & 0xFFFFu;                    \
        unsigned a16 = 0x3800u | ((u16 >> 2) & 0x7FFu);                   \
        unsigned e   = u16 >> 13;                                         \
        unsigned long long sh = (unsigned long long)a16 << ((e & 3u) << 4); \
        unsigned lo = (unsigned)sh, hi = (unsigned)(sh >> 32);            \
        bool c = e < 4;                                                   \
        ux4 q; q.x = c ? lo : 0u; q.y = c ? hi : 0u;                      \
        q.z = c ? 0u : lo; q.w = c ? 0u : hi;                             \
        FR[m][ks].u = q;                                                  \
      }                                                                   \
  } while (0)

  unsigned rB[2];
#pragma unroll
  for (int n = 0; n < 2; ++n)
    rB[n] = (unsigned)((wn * 64 + n * 32 + l31) * 16);

#define COMPUTE(bb, FR) do {                                              \
    const unsigned base = (unsigned)((bb) * 16384) + (unsigned)(lh1 * 2048); \
    _Pragma("unroll")                                                     \
    for (int ks = 0; ks < 4; ++ks) {                                      \
      uq b0, b1;                                                          \
      b0.u = *(const ux4*)(Bc + base + (unsigned)(ks * 4096) + rB[0]);    \
      b1.u = *(const ux4*)(Bc + base + (unsigned)(ks * 4096) + rB[1]);    \
      _Pragma("unroll")                                                   \
      for (int m = 0; m < 2; ++m) {                                       \
        acc[m][0] = __builtin_amdgcn_mfma_f32_32x32x16_bf16(FR[m][ks].s, b0.s, acc[m][0], 0, 0, 0); \
        acc[m][1] = __builtin_amdgcn_mfma_f32_32x32x16_bf16(FR[m][ks].s, b1.s, acc[m][1], 0, 0, 0); \
      }                                                                   \
    }                                                                     \
  } while (0)

  f32x16 acc[2][2];
#pragma unroll
  for (int m = 0; m < 2; ++m)
#pragma unroll
    for (int n = 0; n < 2; ++n) acc[m][n] = 0.f;

  ux4 aE[2], aO[2];
  uq frE[2][4], frO[2][4];

  ISSUE(0, 0, aE);
  ISSUE(1, 1, aO);

  for (int s = 0; s < 32; s += 2) {
    const int sq2 = (s + 2 < 32) ? s + 2 : 31;
    const int sq3 = (s + 3 < 32) ? s + 3 : 31;
    const int b0 = s % 3, b1 = (s + 1) % 3, b2 = (s + 2) % 3;
    // even step s
    asm volatile("s_waitcnt vmcnt(6)" ::: "memory");
    __builtin_amdgcn_s_barrier();
    BUILD(aE, frE);
    ISSUE(sq2, b2, aE);
    __builtin_amdgcn_s_setprio(1);
    COMPUTE(b0, frE);
    __builtin_amdgcn_s_setprio(0);
    // odd step s+1
    asm volatile("s_waitcnt vmcnt(6)" ::: "memory");
    __builtin_amdgcn_s_barrier();
    BUILD(aO, frO);
    ISSUE(sq3, b0, aO);
    __builtin_amdgcn_s_setprio(1);
    COMPUTE(b1, frO);
    __builtin_amdgcn_s_setprio(0);
  }
  asm volatile("s_waitcnt vmcnt(0)" ::: "memory");  // drain before exit

  // epilogue. 32x32 C layout: col = l31, row = (q&3) + 8*(q>>2) + 4*lh1
  if (usePart) {
    _Float16* pp = dstH + ((size_t)kz << 20);
#pragma unroll
    for (int m = 0; m < 2; ++m)
#pragma unroll
      for (int n = 0; n < 2; ++n)
#pragma unroll
        for (int q = 0; q < 16; ++q) {
          int gi = i0 + wm * 64 + m * 32 + (q & 3) + 8 * (q >> 2) + 4 * lh1;
          int go = o0 + wn * 64 + n * 32 + l31;
          pp[(size_t)gi * 256 + go] = (_Float16)acc[m][n][q];
        }
  } else {
#pragma unroll
    for (int m = 0; m < 2; ++m)
#pragma unroll
      for (int n = 0; n < 2; ++n)
#pragma unroll
        for (int q = 0; q < 16; ++q) {
          int gi = i0 + wm * 64 + m * 32 + (q & 3) + 8 * (q >> 2) + 4 * lh1;
          int go = o0 + wn * 64 + n * 32 + l31;
          atomicAdd(dstF + (size_t)gi * 256 + go, acc[m][n][q]);
        }
  }
#undef ISSUE
#undef BUILD
#undef COMPUTE
}

// ---------------- k_red: sum 16 f16 partials + bias -> out ----------------
__global__ __launch_bounds__(256) void k_red(const _Float16* __restrict__ part,
                                             const float* __restrict__ bias,
                                             float* __restrict__ out) {
  int idx = blockIdx.x * 256 + threadIdx.x;     // 262144 fx4-groups
  fx4 s = *(const fx4*)(bias + ((idx << 2) & 255));
#pragma unroll
  for (int k = 0; k < 16; ++k) {
    h4 h = *(const h4*)(part + ((size_t)k << 20) + (size_t)idx * 4);
    s.x += (float)h.x; s.y += (float)h.y; s.z += (float)h.z; s.w += (float)h.w;
  }
  ((fx4*)out)[idx] = s;
}

extern "C" void kernel_launch(void* const* d_in, const int* in_sizes, int n_in,
                              void* d_out, int out_size, void* d_ws, size_t ws_size,
                              hipStream_t stream) {
  const float* x    = (const float*)d_in[0];
  const float* A    = (const float*)d_in[1];
  const int*   et   = (const int*)d_in[2];
  const float* W    = (const float*)d_in[3];
  const float* bias = (const float*)d_in[4];
  float* out = (float*)d_out;

  unsigned short* yt  = (unsigned short*)d_ws;                               // 16 MB
  unsigned short* Apk = (unsigned short*)((char*)d_ws + ((size_t)16 << 20)); // 32 MB
  _Float16*       pp  = (_Float16*)((char*)d_ws + ((size_t)48 << 20));       // 32 MB

  const bool usePart = ws_size >= ((size_t)80 << 20);

  k_prep<<<dim3(1536), dim3(256), 0, stream>>>(A, et, Apk, x, W, yt);
  if (usePart) {
    k_main<<<dim3(1024), dim3(256), 0, stream>>>(Apk, yt, out, pp, 1);
    k_red<<<dim3(1024), dim3(256), 0, stream>>>(pp, bias, out);
  } else {
    k_init<<<dim3(4096), dim3(256), 0, stream>>>(bias, out);
    k_main<<<dim3(1024), dim3(256), 0, stream>>>(Apk, yt, out, pp, 0);
  }
}